// Round 5
// baseline (1413.790 us; speedup 1.0000x reference)
//
#include <hip/hip_runtime.h>
#include <math.h>

// PixelSnail forward, fp32. B=8, CH=1, H=W=32 (N=1024), HID=64, S=8, L=2,
// HEAD=4, QK=16 (d=4/head), VD=32 (8/head).

#define NPix 1024

__device__ __forceinline__ float elu_f(float x){ return x > 0.f ? x : __expf(x) - 1.f; }
__device__ __forceinline__ float sig_f(float x){ return 1.f / (1.f + __expf(-x)); }

// ---------------- weight transpose: bb1 [16][64o][64i]f4 -> [16][64i][64o]f4,
// bb2 [16][128o][64i]f4 -> [16][64i][128o]f4, qkv [8][64c][66i] -> [8][66i][64c]
__global__ __launch_bounds__(256) void k_wT(const float* __restrict__ bb1_w,
        const float* __restrict__ bb2_w, const float* __restrict__ qkv_w,
        float* __restrict__ wT1, float* __restrict__ wT2, float* __restrict__ wTq)
{
    int tid = blockIdx.x*256 + threadIdx.x;
    if (tid < 65536){
        int o = tid & 63, i = (tid>>6) & 63, sl = tid >> 12;
        reinterpret_cast<float4*>(wT1)[tid] =
            reinterpret_cast<const float4*>(bb1_w)[(sl*64 + o)*64 + i];
    }
    int t2 = tid - 65536;
    if (t2 >= 0 && t2 < 131072){
        int o = t2 & 127, i = (t2>>7) & 63, sl = t2 >> 13;
        reinterpret_cast<float4*>(wT2)[t2] =
            reinterpret_cast<const float4*>(bb2_w)[(sl*128 + o)*64 + i];
    }
    int t3 = tid - 196608;
    if (t3 >= 0 && t3 < 33792){
        int c = t3 & 63, rem = t3 >> 6, i = rem % 66, s = rem / 66;
        wTq[t3] = qkv_w[(s*64 + c)*66 + i];
    }
}

// ---------------- stem: masked 3x3 conv, 1->64, taps (0,0)(0,1)(0,2)(1,0) ----
__global__ __launch_bounds__(256) void k_stem(const float* __restrict__ x,
        const float* __restrict__ w, const float* __restrict__ bias,
        float* __restrict__ out, float* __restrict__ e_out)
{
    int b = blockIdx.x >> 5, h = blockIdx.x & 31;
    int t = threadIdx.x;
    int col = t & 31, slot = t >> 5;
    int hw = h*32 + col;
    const float* xb = x + b*NPix;
    float x00=0.f, x01=0.f, x02=0.f, x10=0.f;
    if (h > 0){
        if (col > 0)  x00 = xb[hw-33];
        x01 = xb[hw-32];
        if (col < 31) x02 = xb[hw-31];
    }
    if (col > 0) x10 = xb[hw-1];
    #pragma unroll
    for (int k2=0;k2<8;k2++){
        int o = slot*8 + k2;
        const float* wo = w + o*9;
        float v = bias[o] + wo[0]*x00 + wo[1]*x01 + wo[2]*x02 + wo[3]*x10;
        out[(b*64+o)*NPix + hw] = v;
        e_out[(b*64+o)*NPix + hw] = elu_f(v);
    }
}

// ---------------- bbA: 2x2 causal conv 64->64 on elu'd input, out = elu ----
// grid 256 = b*32 + hp*2 + half, 512 thr = 8 waves; lane=(r,col), 4 out/lane.
// No LDS: col-1 taps via shfl_up, row-1 via second (L1-hot) load.
__global__ __launch_bounds__(512) void k_bbA(const float* __restrict__ ein,
        const float* __restrict__ wT, const float* __restrict__ bias,
        float* __restrict__ t1e)
{
    int blk = blockIdx.x;
    int half = blk & 1, hp = (blk>>1) & 15, b = blk >> 5;
    int t = threadIdx.x;
    int lane = t & 63;
    int r = lane >> 5, col = lane & 31;
    int row = hp*2 + r;
    int og = __builtin_amdgcn_readfirstlane(t >> 6);
    int o0 = half*32 + og*4;
    float acc[4];
    #pragma unroll
    for (int k=0;k<4;k++) acc[k] = bias[o0+k];
    const float4* wq = reinterpret_cast<const float4*>(wT);
    const float* e0p = ein + b*64*NPix + (row-1)*32 + col;
    const float* e1p = ein + b*64*NPix + row*32 + col;
    bool has_up = (row >= 1);
    #pragma unroll 4
    for (int i=0;i<64;i++){
        float g0 = has_up ? e0p[i*NPix] : 0.f;
        float g1 = e1p[i*NPix];
        float a00 = __shfl_up(g0, 1); if (col == 0) a00 = 0.f;
        float a10 = __shfl_up(g1, 1); if (col == 0) a10 = 0.f;
        #pragma unroll
        for (int k=0;k<4;k++){
            float4 wv = wq[i*64 + o0 + k];
            acc[k] = fmaf(wv.x, a00, acc[k]);
            acc[k] = fmaf(wv.y, g0,  acc[k]);
            acc[k] = fmaf(wv.z, a10, acc[k]);
            acc[k] = fmaf(wv.w, g1,  acc[k]);
        }
    }
    int gi = (b*64 + o0)*NPix + row*32 + col;
    #pragma unroll
    for (int k=0;k<4;k++)
        t1e[gi + k*NPix] = elu_f(acc[k]);
}

// ---------------- bbB: 2x2 conv 64->128 + gate x + x1*sig(x2) ----
// grid 512 = b*64 + hp*4 + oq, 512 thr = 8 waves; lane=(r,col);
// lane computes gate channels {c0,c0+1} = conv outputs {c0,c0+1,c0+64,c0+65}.
__global__ __launch_bounds__(512) void k_bbB(const float* __restrict__ ein,
        const float* __restrict__ xres, const float* __restrict__ wT,
        const float* __restrict__ bias,
        float* __restrict__ conv_out, float* __restrict__ e_out)
{
    int blk = blockIdx.x;
    int oq = blk & 3, hp = (blk>>2) & 15, b = blk >> 6;
    int t = threadIdx.x;
    int lane = t & 63;
    int r = lane >> 5, col = lane & 31;
    int row = hp*2 + r;
    int og = __builtin_amdgcn_readfirstlane(t >> 6);
    int c0 = oq*16 + og*2;           // gate channels c0, c0+1
    float y0 = bias[c0], y1 = bias[c0+1];
    float z0 = bias[c0+64], z1 = bias[c0+65];
    const float4* wq = reinterpret_cast<const float4*>(wT);
    const float* e0p = ein + b*64*NPix + (row-1)*32 + col;
    const float* e1p = ein + b*64*NPix + row*32 + col;
    bool has_up = (row >= 1);
    #pragma unroll 4
    for (int i=0;i<64;i++){
        float g0 = has_up ? e0p[i*NPix] : 0.f;
        float g1 = e1p[i*NPix];
        float a00 = __shfl_up(g0, 1); if (col == 0) a00 = 0.f;
        float a10 = __shfl_up(g1, 1); if (col == 0) a10 = 0.f;
        float4 w0 = wq[i*128 + c0];
        float4 w1 = wq[i*128 + c0 + 1];
        float4 w2 = wq[i*128 + c0 + 64];
        float4 w3 = wq[i*128 + c0 + 65];
        y0 = fmaf(w0.x, a00, y0); y0 = fmaf(w0.y, g0, y0);
        y0 = fmaf(w0.z, a10, y0); y0 = fmaf(w0.w, g1, y0);
        y1 = fmaf(w1.x, a00, y1); y1 = fmaf(w1.y, g0, y1);
        y1 = fmaf(w1.z, a10, y1); y1 = fmaf(w1.w, g1, y1);
        z0 = fmaf(w2.x, a00, z0); z0 = fmaf(w2.y, g0, z0);
        z0 = fmaf(w2.z, a10, z0); z0 = fmaf(w2.w, g1, z0);
        z1 = fmaf(w3.x, a00, z1); z1 = fmaf(w3.y, g0, z1);
        z1 = fmaf(w3.z, a10, z1); z1 = fmaf(w3.w, g1, z1);
    }
    int gi0 = (b*64 + c0)*NPix + row*32 + col;
    float v0 = fmaf(y0, sig_f(z0), xres[gi0]);
    float v1 = fmaf(y1, sig_f(z1), xres[gi0 + NPix]);
    conv_out[gi0] = v0;        conv_out[gi0 + NPix] = v1;
    e_out[gi0]    = elu_f(v0); e_out[gi0 + NPix]    = elu_f(v1);
}

// ---------------- qkv 1x1: (conv 64ch + pos 2ch) -> q/k/v head layouts ----
__global__ __launch_bounds__(256) void k_qkv(const float* __restrict__ conv,
        const float* __restrict__ wt, const float* __restrict__ bias,
        float* __restrict__ qb, float* __restrict__ kb, float* __restrict__ vb)
{
    __shared__ float cl[66*64];
    int blk = blockIdx.x;
    int ohalf = blk & 1, tile = (blk>>1) & 15, b = blk >> 5;
    int hw0 = tile*64;
    int t = threadIdx.x;
    #pragma unroll
    for (int p=0;p<16;p++){
        int idx = t + p*256;
        int i = idx >> 6, px = idx & 63;
        cl[i*64 + px] = conv[(b*64+i)*NPix + hw0 + px];
    }
    if (t < 128){
        int px = t & 63;
        int hw = hw0 + px;
        float v = (t < 64) ? ((float)(hw>>5)*(1.f/32.f) - 0.5f)
                           : ((float)(hw&31)*(1.f/32.f) - 0.5f);
        cl[(64 + (t>>6))*64 + px] = v;
    }
    __syncthreads();
    int px = t & 63;
    int og = __builtin_amdgcn_readfirstlane(t >> 6);
    int c0 = ohalf*32 + og*8;
    int hw = hw0 + px;
    float acc[8];
    #pragma unroll
    for (int k=0;k<8;k++) acc[k] = bias[c0+k];
    #pragma unroll 2
    for (int i=0;i<66;i++){
        float e = cl[i*64 + px];
        #pragma unroll
        for (int k=0;k<8;k++)
            acc[k] = fmaf(wt[i*64 + c0 + k], e, acc[k]);
    }
    float4 f0 = {acc[0],acc[1],acc[2],acc[3]};
    float4 f1 = {acc[4],acc[5],acc[6],acc[7]};
    if (c0 < 32){
        float* dst = (c0 < 16) ? qb : kb;
        int cc = c0 & 15;
        reinterpret_cast<float4*>(dst)[(b*4 + (cc>>2))*NPix + hw] = f0;
        reinterpret_cast<float4*>(dst)[(b*4 + (cc>>2) + 1)*NPix + hw] = f1;
    } else {
        int c2 = c0 - 32;
        reinterpret_cast<float4*>(vb)[((b*4 + (c2>>3))*NPix + hw)*2]     = f0;
        reinterpret_cast<float4*>(vb)[((b*4 + (c2>>3))*NPix + hw)*2 + 1] = f1;
    }
}

// ---------------- causal attention: lane = query, uniform key index (scalar
// loads), per-lane softmax accum (no max-sub, no cross-lane reduce).
// grid 256 = bh*8 + p; 512 thr = 8 waves. Tiles ta=p, tb=15-p (64 queries each).
// Wave w takes 1/8 of both tiles' key ranges: exactly 8*(p+1)+8*(16-p)=136 iters.
__global__ __launch_bounds__(512) void k_attn(const float* __restrict__ qb,
        const float* __restrict__ kb, const float* __restrict__ vb,
        float* __restrict__ ob)
{
    __shared__ float part[8][128][9];   // 36 KB
    int bh = blockIdx.x >> 3, p = blockIdx.x & 7;
    int ta = p, tb = 15 - p;
    int t = threadIdx.x;
    int lane = t & 63;
    int w = __builtin_amdgcn_readfirstlane(t >> 6);
    const float4* k4 = reinterpret_cast<const float4*>(kb) + bh*NPix;
    const float4* v4 = reinterpret_cast<const float4*>(vb) + bh*NPix*2;
    const float4* q4 = reinterpret_cast<const float4*>(qb) + bh*NPix;

    // --- tile A ---
    int qa = ta*64 + lane;
    float4 qva = q4[qa];
    float lsa = 0.f;
    float4 a0 = {0,0,0,0}, a1 = {0,0,0,0};
    int lenA = 8*(ta+1);
    int j0 = w*lenA, j1 = j0 + lenA;
    #pragma unroll 4
    for (int j = j0; j < j1; ++j){
        float4 kk = k4[j];
        float s = 0.5f*(qva.x*kk.x + qva.y*kk.y + qva.z*kk.z + qva.w*kk.w);
        float pe = (j <= qa) ? __expf(s) : 0.f;
        float4 v0 = v4[2*j], v1 = v4[2*j+1];
        lsa += pe;
        a0.x = fmaf(pe, v0.x, a0.x); a0.y = fmaf(pe, v0.y, a0.y);
        a0.z = fmaf(pe, v0.z, a0.z); a0.w = fmaf(pe, v0.w, a0.w);
        a1.x = fmaf(pe, v1.x, a1.x); a1.y = fmaf(pe, v1.y, a1.y);
        a1.z = fmaf(pe, v1.z, a1.z); a1.w = fmaf(pe, v1.w, a1.w);
    }
    // --- tile B ---
    int qbq = tb*64 + lane;
    float4 qvb = q4[qbq];
    float lsb = 0.f;
    float4 b0 = {0,0,0,0}, b1 = {0,0,0,0};
    int lenB = 8*(tb+1);
    int j2 = w*lenB, j3 = j2 + lenB;
    #pragma unroll 4
    for (int j = j2; j < j3; ++j){
        float4 kk = k4[j];
        float s = 0.5f*(qvb.x*kk.x + qvb.y*kk.y + qvb.z*kk.z + qvb.w*kk.w);
        float pe = (j <= qbq) ? __expf(s) : 0.f;
        float4 v0 = v4[2*j], v1 = v4[2*j+1];
        lsb += pe;
        b0.x = fmaf(pe, v0.x, b0.x); b0.y = fmaf(pe, v0.y, b0.y);
        b0.z = fmaf(pe, v0.z, b0.z); b0.w = fmaf(pe, v0.w, b0.w);
        b1.x = fmaf(pe, v1.x, b1.x); b1.y = fmaf(pe, v1.y, b1.y);
        b1.z = fmaf(pe, v1.z, b1.z); b1.w = fmaf(pe, v1.w, b1.w);
    }
    // --- stash partials ---
    float* pa = part[w][lane];
    pa[0]=lsa; pa[1]=a0.x; pa[2]=a0.y; pa[3]=a0.z; pa[4]=a0.w;
    pa[5]=a1.x; pa[6]=a1.y; pa[7]=a1.z; pa[8]=a1.w;
    float* pbp = part[w][64+lane];
    pbp[0]=lsb; pbp[1]=b0.x; pbp[2]=b0.y; pbp[3]=b0.z; pbp[4]=b0.w;
    pbp[5]=b1.x; pbp[6]=b1.y; pbp[7]=b1.z; pbp[8]=b1.w;
    __syncthreads();
    // --- combine: thread per query (128 active) ---
    if (t < 128){
        float s9[9];
        #pragma unroll
        for (int c=0;c<9;c++) s9[c] = part[0][t][c];
        #pragma unroll
        for (int ww=1;ww<8;ww++)
            #pragma unroll
            for (int c=0;c<9;c++) s9[c] += part[ww][t][c];
        float inv = 1.f / s9[0];
        int q = (t < 64) ? ta*64 + t : tb*64 + (t - 64);
        float4 r0 = {s9[1]*inv, s9[2]*inv, s9[3]*inv, s9[4]*inv};
        float4 r1 = {s9[5]*inv, s9[6]*inv, s9[7]*inv, s9[8]*inv};
        float4* od = reinterpret_cast<float4*>(ob);
        od[(bh*NPix + q)*2]     = r0;
        od[(bh*NPix + q)*2 + 1] = r1;
    }
}

// ---------------- epilogue: proj -> outa | outc | outp chain + residual ----
__global__ __launch_bounds__(256) void k_epi(const float* __restrict__ ob,
        const float* __restrict__ conv_raw, float* __restrict__ out,
        const float* __restrict__ pw,  const float* __restrict__ pb,
        const float* __restrict__ cw,  const float* __restrict__ cb2,
        const float* __restrict__ aw,  const float* __restrict__ ab,
        const float* __restrict__ ppw, const float* __restrict__ ppb,
        float* __restrict__ e_out)
{
    __shared__ float s_x[64][33];
    __shared__ float s_ov[32][33];
    __shared__ float s_e1[64][33];
    __shared__ float s_g[64][33];
    __shared__ float wl[14336];
    int b = blockIdx.x >> 5;
    int hw0 = (blockIdx.x & 31) * 32;
    int t = threadIdx.x;
    for (int idx = t; idx < 64*32; idx += 256){
        int i = idx >> 5, px = idx & 31;
        s_x[i][px] = elu_f(conv_raw[(b*64+i)*NPix + hw0 + px]);
    }
    for (int idx = t; idx < 32*32; idx += 256){
        int c = idx >> 5, px = idx & 31;
        s_ov[c][px] = ob[(b*4 + (c>>3))*NPix*8 + (hw0+px)*8 + (c&7)];
    }
    {
        float4* wl4 = reinterpret_cast<float4*>(wl);
        for (int idx = t; idx < 512; idx += 256)
            wl4[idx] = reinterpret_cast<const float4*>(pw)[idx];
        for (int idx = t; idx < 1024; idx += 256){
            wl4[512 + idx]  = reinterpret_cast<const float4*>(cw)[idx];
            wl4[1536 + idx] = reinterpret_cast<const float4*>(aw)[idx];
            wl4[2560 + idx] = reinterpret_cast<const float4*>(ppw)[idx];
        }
    }
    __syncthreads();
    int px = t & 31, g = t >> 5;
    int o0 = g*8;
    const float4* wp4  = reinterpret_cast<const float4*>(wl);
    const float4* wc4  = reinterpret_cast<const float4*>(wl + 2048);
    const float4* wa4  = reinterpret_cast<const float4*>(wl + 6144);
    const float4* wpp4 = reinterpret_cast<const float4*>(wl + 10240);
    float acc[8];
    #pragma unroll
    for (int k=0;k<8;k++) acc[k] = pb[o0+k];
    #pragma unroll
    for (int i4=0;i4<8;i4++){
        float v0 = s_ov[i4*4+0][px], v1 = s_ov[i4*4+1][px];
        float v2 = s_ov[i4*4+2][px], v3 = s_ov[i4*4+3][px];
        #pragma unroll
        for (int k=0;k<8;k++){
            float4 wv = wp4[(o0+k)*8 + i4];
            acc[k] = fmaf(wv.x, v0, acc[k]); acc[k] = fmaf(wv.y, v1, acc[k]);
            acc[k] = fmaf(wv.z, v2, acc[k]); acc[k] = fmaf(wv.w, v3, acc[k]);
        }
    }
    #pragma unroll
    for (int k=0;k<8;k++) s_e1[o0+k][px] = elu_f(acc[k]);
    __syncthreads();
    float aa[8], cc[8];
    #pragma unroll
    for (int k=0;k<8;k++){ aa[k] = ab[o0+k]; cc[k] = cb2[o0+k]; }
    #pragma unroll
    for (int i4=0;i4<16;i4++){
        float e0 = s_e1[i4*4+0][px], e1 = s_e1[i4*4+1][px];
        float e2 = s_e1[i4*4+2][px], e3 = s_e1[i4*4+3][px];
        float x0 = s_x[i4*4+0][px],  x1 = s_x[i4*4+1][px];
        float x2 = s_x[i4*4+2][px],  x3 = s_x[i4*4+3][px];
        #pragma unroll
        for (int k=0;k<8;k++){
            float4 wa = wa4[(o0+k)*16 + i4];
            float4 wc = wc4[(o0+k)*16 + i4];
            aa[k] = fmaf(wa.x, e0, aa[k]); aa[k] = fmaf(wa.y, e1, aa[k]);
            aa[k] = fmaf(wa.z, e2, aa[k]); aa[k] = fmaf(wa.w, e3, aa[k]);
            cc[k] = fmaf(wc.x, x0, cc[k]); cc[k] = fmaf(wc.y, x1, cc[k]);
            cc[k] = fmaf(wc.z, x2, cc[k]); cc[k] = fmaf(wc.w, x3, cc[k]);
        }
    }
    #pragma unroll
    for (int k=0;k<8;k++) s_g[o0+k][px] = elu_f(elu_f(aa[k]) + elu_f(cc[k]));
    __syncthreads();
    float bl[8];
    #pragma unroll
    for (int k=0;k<8;k++) bl[k] = ppb[o0+k];
    #pragma unroll
    for (int i4=0;i4<16;i4++){
        float g0 = s_g[i4*4+0][px], g1 = s_g[i4*4+1][px];
        float g2 = s_g[i4*4+2][px], g3 = s_g[i4*4+3][px];
        #pragma unroll
        for (int k=0;k<8;k++){
            float4 wv = wpp4[(o0+k)*16 + i4];
            bl[k] = fmaf(wv.x, g0, bl[k]); bl[k] = fmaf(wv.y, g1, bl[k]);
            bl[k] = fmaf(wv.z, g2, bl[k]); bl[k] = fmaf(wv.w, g3, bl[k]);
        }
    }
    #pragma unroll
    for (int k=0;k<8;k++){
        int gi = (b*64 + o0 + k)*NPix + hw0 + px;
        float on = elu_f(bl[k]) + out[gi];
        out[gi] = on;
        e_out[gi] = elu_f(on);
    }
}

// ---------------- final 1x1: logits = fc_w . elu(out) + fc_b ----
__global__ __launch_bounds__(256) void k_final(const float* __restrict__ out,
        const float* __restrict__ fw, const float* __restrict__ fb,
        float* __restrict__ logits)
{
    int idx = blockIdx.x*256 + threadIdx.x;      // 65536
    int pix = idx >> 3, sub = idx & 7;
    int b = pix >> 10, hw = pix & 1023;
    const float* obp = out + b*64*NPix + hw;
    float acc = 0.f;
    #pragma unroll
    for (int k=0;k<8;k++){
        int i = sub*8 + k;
        acc = fmaf(fw[i], elu_f(obp[i*NPix]), acc);
    }
    #pragma unroll
    for (int off=1; off<8; off<<=1) acc += __shfl_xor(acc, off);
    if (sub == 0) logits[pix] = acc + fb[0];
}

extern "C" void kernel_launch(void* const* d_in, const int* in_sizes, int n_in,
                              void* d_out, int out_size, void* d_ws, size_t ws_size,
                              hipStream_t stream)
{
    const float* x      = (const float*)d_in[0];
    const float* stem_w = (const float*)d_in[1];
    const float* stem_b = (const float*)d_in[2];
    const float* bb1_w  = (const float*)d_in[3];
    const float* bb1_b  = (const float*)d_in[4];
    const float* bb2_w  = (const float*)d_in[5];
    const float* bb2_b  = (const float*)d_in[6];
    const float* qkv_w  = (const float*)d_in[7];
    const float* qkv_b  = (const float*)d_in[8];
    const float* proj_w = (const float*)d_in[9];
    const float* proj_b = (const float*)d_in[10];
    const float* outc_w = (const float*)d_in[11];
    const float* outc_b = (const float*)d_in[12];
    const float* outa_w = (const float*)d_in[13];
    const float* outa_b = (const float*)d_in[14];
    const float* outp_w = (const float*)d_in[15];
    const float* outp_b = (const float*)d_in[16];
    const float* fc_w   = (const float*)d_in[17];
    const float* fc_b   = (const float*)d_in[18];
    float* logits = (float*)d_out;

    float* W        = (float*)d_ws;
    float* out_buf  = W;                  // B*64*N = 524288
    float* e_conv   = W + 524288;
    float* conv_raw = W + 2*524288;
    float* t1e      = W + 3*524288;
    float* qbuf     = W + 4*524288;       // [b][h][n][4]
    float* kbuf     = qbuf + 131072;
    float* vbuf     = kbuf + 131072;      // [b][h][n][8]
    float* obuf     = vbuf + 262144;      // [b][h][n][8]
    float* wT1      = obuf + 262144;      // 16*64*64*4 = 262144
    float* wT2      = wT1 + 262144;       // 16*64*128*4 = 524288
    float* wTq      = wT2 + 524288;       // 8*66*64 = 33792

    k_wT<<<900,256,0,stream>>>(bb1_w, bb2_w, qkv_w, wT1, wT2, wTq);
    k_stem<<<256,256,0,stream>>>(x, stem_w, stem_b, out_buf, e_conv);
    for (int s=0;s<8;s++){
        for (int l=0;l<2;l++){
            int sl = s*2+l;
            k_bbA<<<256,512,0,stream>>>(e_conv, wT1 + sl*16384, bb1_b + sl*64, t1e);
            const float* xres = (l==0) ? out_buf : conv_raw;
            k_bbB<<<512,512,0,stream>>>(t1e, xres, wT2 + sl*32768, bb2_b + sl*128,
                                        conv_raw, e_conv);
        }
        k_qkv<<<256,256,0,stream>>>(conv_raw, wTq + s*4224, qkv_b + s*64,
                                    qbuf, kbuf, vbuf);
        k_attn<<<256,512,0,stream>>>(qbuf, kbuf, vbuf, obuf);
        k_epi<<<256,256,0,stream>>>(obuf, conv_raw, out_buf,
                                    proj_w + s*2048, proj_b + s*64,
                                    outc_w + s*4096, outc_b + s*64,
                                    outa_w + s*4096, outa_b + s*64,
                                    outp_w + s*4096, outp_b + s*64,
                                    e_conv);
    }
    k_final<<<256,256,0,stream>>>(out_buf, fc_w, fc_b, logits);
}